// Round 1
// baseline (781.368 us; speedup 1.0000x reference)
//
#include <hip/hip_runtime.h>
#include <math.h>

#define NB 4
#define NR 4096
#define NS 48
#define PLANE_ELEMS (65536*32)   // H*W*C per (b,plane)

__device__ __forceinline__ float coarse_depth(float cam, int i) {
    float nearv = cam - 0.5f;
    float farv  = cam + 0.5f;
    float t = ((float)i + 0.5f) / 48.0f;
    return nearv + (farv - nearv) * t;
}
__device__ __forceinline__ float softplusf(float x) {
    return fmaxf(x, 0.0f) + __logf(1.0f + __expf(-fabsf(x)));
}
__device__ __forceinline__ float sigmoidf(float x) {
    return 1.0f / (1.0f + __expf(-x));
}

// K0: transpose planes [bp][C][H][W] -> [bp][H][W][C] for contiguous per-texel channels
__global__ __launch_bounds__(256) void k_transpose(const float* __restrict__ src,
                                                   float* __restrict__ dst) {
    __shared__ float tile[256*33];
    int row = blockIdx.x;          // bp*256 + y
    int bp  = row >> 8;
    int y   = row & 255;
    int x   = threadIdx.x;
    const float* s = src + (size_t)bp*PLANE_ELEMS + (size_t)y*256;
    #pragma unroll
    for (int c = 0; c < 32; ++c) tile[x*33 + c] = s[(size_t)c*65536 + x];
    __syncthreads();
    float* d = dst + ((size_t)bp*65536 + (size_t)y*256)*32;
    #pragma unroll
    for (int it = 0; it < 32; ++it) {
        int idx = it*256 + x;                       // 0..8191 within row: [x][c]
        d[idx] = tile[(idx >> 5)*33 + (idx & 31)];
    }
}

// K1/K3: plane sampling + decoder MLP. mode 0 = coarse depths (closed form),
// mode 1 = fine depths from buffer. One block = 256 points.
__global__ __launch_bounds__(256) void k_sample_mlp(
    const float* __restrict__ planes, const float* __restrict__ planesT,
    const float* __restrict__ orig, const float* __restrict__ dirs,
    const float* __restrict__ w1, const float* __restrict__ b1,
    const float* __restrict__ w2, const float* __restrict__ b2,
    const float* __restrict__ dfine,
    float* __restrict__ colors, float* __restrict__ sigmas,
    int mode, int chlast)
{
    __shared__ float desc_w[256][3][4];
    __shared__ int   desc_o[256][3][4];
    __shared__ float featT[32*257];   // [c][point], pad 257 -> 2-way-free banks

    int tid = threadIdx.x;
    int pid = blockIdx.x * 256 + tid;
    int rid = pid / 48;
    int s   = pid - rid*48;
    int b   = rid >> 12;              // rid / 4096

    // ---- phase 0: per-point tap descriptors ----
    float ox = orig[rid*3+0], oy = orig[rid*3+1], oz = orig[rid*3+2];
    float dxv = dirs[rid*3+0], dyv = dirs[rid*3+1], dzv = dirs[rid*3+2];
    float depth;
    if (mode == 0) {
        float cam = sqrtf(ox*ox + oy*oy + oz*oz);
        depth = coarse_depth(cam, s);
    } else {
        depth = dfine[(size_t)rid*48 + s];
    }
    float cx = ox + depth*dxv;
    float cy = oy + depth*dyv;
    float cz = oz + depth*dzv;
    // plane projections: p0 (x,y), p1 (z,x), p2 (y,z)
    float us[3] = {cx, cz, cy};
    float vs[3] = {cy, cx, cz};
    #pragma unroll
    for (int pl = 0; pl < 3; ++pl) {
        float xg = (us[pl] + 1.0f) * 0.5f * 256.0f - 0.5f;
        float yg = (vs[pl] + 1.0f) * 0.5f * 256.0f - 0.5f;
        float x0f = floorf(xg), y0f = floorf(yg);
        float wx = xg - x0f, wy = yg - y0f;
        int x0 = (int)x0f, y0 = (int)y0f;
        float tw[4] = {(1.0f-wx)*(1.0f-wy), wx*(1.0f-wy), (1.0f-wx)*wy, wx*wy};
        #pragma unroll
        for (int t4 = 0; t4 < 4; ++t4) {
            int xi = x0 + (t4 & 1);
            int yi = y0 + (t4 >> 1);
            bool valid = (xi >= 0) && (xi < 256) && (yi >= 0) && (yi < 256);
            int xc = min(max(xi, 0), 255);
            int yc = min(max(yi, 0), 255);
            desc_w[tid][pl][t4] = valid ? tw[t4] : 0.0f;
            desc_o[tid][pl][t4] = yc*256 + xc;
        }
    }
    __syncthreads();

    // ---- phase 1: cooperative gather, 8 lanes per point (4 channels/lane) ----
    int g = tid >> 3, sub = tid & 7;
    int c0 = sub * 4;
    size_t pbase = (size_t)(b*3) * PLANE_ELEMS;
    #pragma unroll 2
    for (int it = 0; it < 8; ++it) {
        int pp = it*32 + g;
        float a0=0.f, a1=0.f, a2=0.f, a3=0.f;
        #pragma unroll
        for (int pl = 0; pl < 3; ++pl) {
            size_t base = pbase + (size_t)pl*PLANE_ELEMS;
            #pragma unroll
            for (int t4 = 0; t4 < 4; ++t4) {
                float wv = desc_w[pp][pl][t4];
                int tix  = desc_o[pp][pl][t4];
                if (chlast) {
                    const float4 v = *reinterpret_cast<const float4*>(
                        planesT + base + (size_t)tix*32 + c0);
                    a0 = fmaf(wv, v.x, a0);
                    a1 = fmaf(wv, v.y, a1);
                    a2 = fmaf(wv, v.z, a2);
                    a3 = fmaf(wv, v.w, a3);
                } else {
                    const float* bp = planes + base + tix;
                    a0 = fmaf(wv, bp[(size_t)(c0+0)*65536], a0);
                    a1 = fmaf(wv, bp[(size_t)(c0+1)*65536], a1);
                    a2 = fmaf(wv, bp[(size_t)(c0+2)*65536], a2);
                    a3 = fmaf(wv, bp[(size_t)(c0+3)*65536], a3);
                }
            }
        }
        const float inv3 = 1.0f/3.0f;   // mean over the 3 planes
        featT[(c0+0)*257 + pp] = a0*inv3;
        featT[(c0+1)*257 + pp] = a1*inv3;
        featT[(c0+2)*257 + pp] = a2*inv3;
        featT[(c0+3)*257 + pp] = a3*inv3;
    }
    __syncthreads();

    // ---- phase 2: MLP (w1/w2 wave-uniform -> scalar loads) ----
    float h[64];
    #pragma unroll
    for (int j = 0; j < 64; ++j) h[j] = b1[j];
    for (int k = 0; k < 32; ++k) {
        float xk = featT[k*257 + tid];
        #pragma unroll
        for (int j = 0; j < 64; ++j) h[j] = fmaf(xk, w1[k*64 + j], h[j]);
    }
    #pragma unroll
    for (int j = 0; j < 64; ++j) h[j] = softplusf(h[j]);
    float o0 = b2[0], o1 = b2[1], o2 = b2[2], o3 = b2[3];
    for (int j = 0; j < 64; ++j) {
        float hv = h[j];
        o0 = fmaf(hv, w2[j*4+0], o0);
        o1 = fmaf(hv, w2[j*4+1], o1);
        o2 = fmaf(hv, w2[j*4+2], o2);
        o3 = fmaf(hv, w2[j*4+3], o3);
    }
    float sigma = 10.0f * softplusf(-10.0f * o0);
    float r0 = sigmoidf(o1)*1.002f - 0.001f;
    float r1 = sigmoidf(o2)*1.002f - 0.001f;
    float r2 = sigmoidf(o3)*1.002f - 0.001f;
    int slot = rid*96 + (mode ? 48 + s : s);
    colors[(size_t)slot*3+0] = r0;
    colors[(size_t)slot*3+1] = r1;
    colors[(size_t)slot*3+2] = r2;
    sigmas[slot] = sigma;
}

// K2: per-ray coarse ray-march weights -> blurred pdf -> inverse-CDF fine depths
__global__ __launch_bounds__(256) void k_importance(
    const float* __restrict__ orig, const float* __restrict__ sigmas,
    float* __restrict__ dfine)
{
    __shared__ float tile[256*49];
    int t  = threadIdx.x;
    int r0 = blockIdx.x * 256;
    for (int it = 0; it < 48; ++it) {           // stage sigma coalesced
        int l  = it*256 + t;
        int ri = l / 48;
        int i  = l - ri*48;
        tile[ri*49 + i] = sigmas[(size_t)(r0+ri)*96 + i];
    }
    __syncthreads();
    int rid = r0 + t;
    float ox = orig[rid*3+0], oy = orig[rid*3+1], oz = orig[rid*3+2];
    float cam = sqrtf(ox*ox + oy*oy + oz*oz);

    float w[47];
    float T = 1.0f;
    float sp_ = tile[t*49 + 0];
    float dprev = coarse_depth(cam, 0);
    #pragma unroll
    for (int i = 0; i < 47; ++i) {
        float sc = tile[t*49 + i + 1];
        float dnext = coarse_depth(cam, i+1);
        float delta = dnext - dprev;
        float dm = 0.5f*(sp_ + sc);
        float a = 1.0f - __expf(-delta*dm);
        w[i] = a * T;
        T *= (1.0f - a + 1e-10f);
        sp_ = sc; dprev = dnext;
    }
    // blurred weights (wb[1..45]) + eps, reuse own tile row for dynamic access
    float Ssum = 0.0f;
    #pragma unroll
    for (int m = 0; m < 45; ++m) {
        float wm1 = fmaxf(w[m],   w[m+1]);
        float wm2 = fmaxf(w[m+1], w[m+2]);
        float wq = (0.5f*(wm1 + wm2) + 0.01f) + 1e-5f;
        tile[t*49 + m] = wq;
        Ssum += wq;
    }
    // streaming searchsorted(cdf, u, 'right'); u monotone
    int idx = 1;
    float cprev = 0.0f;
    float ccur  = tile[t*49 + 0] / Ssum;        // cdf[1]
    for (int k = 0; k < 48; ++k) {
        float u = (float)k * (1.0f/47.0f);
        while (idx < 46 && ccur <= u) {
            cprev = ccur;
            idx++;
            if (idx < 46) ccur += tile[t*49 + (idx-1)] / Ssum;
        }
        int below = idx - 1;
        int above = min(idx, 45);
        float cb = cprev;
        float ca = (idx < 46) ? ccur : cprev;
        float bb = 0.5f*(coarse_depth(cam, below) + coarse_depth(cam, below+1));
        float ba = 0.5f*(coarse_depth(cam, above) + coarse_depth(cam, above+1));
        float d_ = ca - cb;
        float den = (d_ < 1e-5f) ? 1.0f : d_;
        dfine[(size_t)rid*48 + k] = bb + (u - cb)/den * (ba - bb);
    }
}

// K4: stable merge of sorted coarse+fine depths fused with final ray march
__global__ __launch_bounds__(64) void k_final(
    const float* __restrict__ orig,
    const float* __restrict__ colors, const float* __restrict__ sigmas,
    const float* __restrict__ dfine, float* __restrict__ out)
{
    int rid = blockIdx.x*64 + threadIdx.x;
    float ox = orig[rid*3+0], oy = orig[rid*3+1], oz = orig[rid*3+2];
    float cam = sqrtf(ox*ox + oy*oy + oz*oz);
    int i = 0, j = 0;
    float T = 1.0f, rgb0=0.f, rgb1=0.f, rgb2=0.f, dep=0.f, wsum=0.f;
    float dprev=0.f, sprev=0.f, cp0=0.f, cp1=0.f, cp2=0.f;
    for (int m = 0; m < 96; ++m) {
        float dc = (i < 48) ? coarse_depth(cam, i) : 3.4e38f;
        float df = (j < 48) ? dfine[(size_t)rid*48 + j] : 3.4e38f;
        bool takec = dc <= df;                  // stable: coarse first on ties
        int slot = rid*96 + (takec ? i : 48 + j);
        float dcur = takec ? dc : df;
        if (takec) ++i; else ++j;
        float sc = sigmas[slot];
        float c0 = colors[(size_t)slot*3+0];
        float c1 = colors[(size_t)slot*3+1];
        float c2 = colors[(size_t)slot*3+2];
        if (m > 0) {
            float delta = dcur - dprev;
            float dm = 0.5f*(sprev + sc);
            float zm = 0.5f*(dprev + dcur);
            float a = 1.0f - __expf(-delta*dm);
            float wgt = a * T;
            T *= (1.0f - a + 1e-10f);
            rgb0 += wgt*0.5f*(cp0 + c0);
            rgb1 += wgt*0.5f*(cp1 + c1);
            rgb2 += wgt*0.5f*(cp2 + c2);
            dep  += wgt*zm;
            wsum += wgt;
        }
        dprev = dcur; sprev = sc; cp0 = c0; cp1 = c1; cp2 = c2;
    }
    out[rid*3+0] = rgb0;
    out[rid*3+1] = rgb1;
    out[rid*3+2] = rgb2;
    out[16384*3 + rid] = dep;   // depth_final region
    out[16384*4 + rid] = wsum;  // weight-sum region
}

extern "C" void kernel_launch(void* const* d_in, const int* in_sizes, int n_in,
                              void* d_out, int out_size, void* d_ws, size_t ws_size,
                              hipStream_t stream)
{
    const float* planes = (const float*)d_in[0];
    const float* orig   = (const float*)d_in[1];
    const float* dirs   = (const float*)d_in[2];
    const float* w1     = (const float*)d_in[3];
    const float* b1     = (const float*)d_in[4];
    const float* w2     = (const float*)d_in[5];
    const float* b2     = (const float*)d_in[6];
    float* out = (float*)d_out;

    float* ws = (float*)d_ws;
    size_t n_sig = (size_t)NB*NR*96;     // 1,572,864
    size_t n_col = n_sig*3;              // 4,718,592
    size_t n_df  = (size_t)NB*NR*48;     //   786,432
    float* sig     = ws;
    float* col     = sig + n_sig;
    float* dfin    = col + n_col;
    float* planesT = dfin + n_df;
    size_t need = (n_sig + n_col + n_df + (size_t)12*PLANE_ELEMS) * sizeof(float);
    int chlast = (ws_size >= need) ? 1 : 0;

    if (chlast)
        k_transpose<<<12*256, 256, 0, stream>>>(planes, planesT);
    k_sample_mlp<<<3072, 256, 0, stream>>>(planes, planesT, orig, dirs,
                                           w1, b1, w2, b2, dfin, col, sig, 0, chlast);
    k_importance<<<64, 256, 0, stream>>>(orig, sig, dfin);
    k_sample_mlp<<<3072, 256, 0, stream>>>(planes, planesT, orig, dirs,
                                           w1, b1, w2, b2, dfin, col, sig, 1, chlast);
    k_final<<<256, 64, 0, stream>>>(orig, col, sig, dfin, out);
}

// Round 2
// 536.190 us; speedup vs baseline: 1.4573x; 1.4573x over previous
//
#include <hip/hip_runtime.h>
#include <math.h>

#define NB 4
#define NR 4096
#define NS 48
#define PLANE_ELEMS (65536*32)   // H*W*C per (b,plane)

__device__ __forceinline__ float coarse_depth(float cam, int i) {
    float nearv = cam - 0.5f;
    float farv  = cam + 0.5f;
    float t = ((float)i + 0.5f) / 48.0f;
    return nearv + (farv - nearv) * t;
}
__device__ __forceinline__ float softplusf(float x) {
    return fmaxf(x, 0.0f) + __logf(1.0f + __expf(-fabsf(x)));
}
__device__ __forceinline__ float sigmoidf(float x) {
    return 1.0f / (1.0f + __expf(-x));
}

// K0: transpose planes [bp][C][H][W] -> [bp][H][W][C]
__global__ __launch_bounds__(256) void k_transpose(const float* __restrict__ src,
                                                   float* __restrict__ dst) {
    __shared__ float tile[256*33];
    int row = blockIdx.x;          // bp*256 + y
    int bp  = row >> 8;
    int y   = row & 255;
    int x   = threadIdx.x;
    const float* s = src + (size_t)bp*PLANE_ELEMS + (size_t)y*256;
    #pragma unroll
    for (int c = 0; c < 32; ++c) tile[x*33 + c] = s[(size_t)c*65536 + x];
    __syncthreads();
    float* d = dst + ((size_t)bp*65536 + (size_t)y*256)*32;
    #pragma unroll
    for (int it = 0; it < 32; ++it) {
        int idx = it*256 + x;                       // [x][c]
        d[idx] = tile[(idx >> 5)*33 + (idx & 31)];
    }
}

// K1/K3: plane sampling + decoder MLP. One block = 256 points.
// Tap descriptors live in the owner lane's registers; gather lanes pull them
// via __shfl (each wave gathers only its own 64 points). LDS = featT only
// (32.9 KB) -> 4 blocks/CU (was 2 with desc arrays in LDS).
__global__ __launch_bounds__(256, 4) void k_sample_mlp(
    const float* __restrict__ planesT,
    const float* __restrict__ orig, const float* __restrict__ dirs,
    const float* __restrict__ w1, const float* __restrict__ b1,
    const float* __restrict__ w2, const float* __restrict__ b2,
    const float* __restrict__ dfine,
    float* __restrict__ colors, float* __restrict__ sigmas,
    int mode)
{
    __shared__ float featT[32*257];   // [c][point]

    int tid = threadIdx.x;
    int pid = blockIdx.x * 256 + tid;
    int rid = pid / 48;
    int s   = pid - rid*48;
    int b   = rid >> 12;              // uniform per block (768 blocks/batch)

    // ---- phase 0: this thread's point -> 12 tap descriptors in registers ----
    float ox = orig[rid*3+0], oy = orig[rid*3+1], oz = orig[rid*3+2];
    float dxv = dirs[rid*3+0], dyv = dirs[rid*3+1], dzv = dirs[rid*3+2];
    float depth;
    if (mode == 0) {
        float cam = sqrtf(ox*ox + oy*oy + oz*oz);
        depth = coarse_depth(cam, s);
    } else {
        depth = dfine[(size_t)rid*48 + s];
    }
    float cx = ox + depth*dxv;
    float cy = oy + depth*dyv;
    float cz = oz + depth*dzv;
    // plane projections: p0 (x,y), p1 (z,x), p2 (y,z)
    float us[3] = {cx, cz, cy};
    float vs[3] = {cy, cx, cz};
    float dw[12];
    int   dof[12];
    #pragma unroll
    for (int pl = 0; pl < 3; ++pl) {
        float xg = (us[pl] + 1.0f) * 0.5f * 256.0f - 0.5f;
        float yg = (vs[pl] + 1.0f) * 0.5f * 256.0f - 0.5f;
        float x0f = floorf(xg), y0f = floorf(yg);
        float wx = xg - x0f, wy = yg - y0f;
        int x0 = (int)x0f, y0 = (int)y0f;
        float tw[4] = {(1.0f-wx)*(1.0f-wy), wx*(1.0f-wy), (1.0f-wx)*wy, wx*wy};
        #pragma unroll
        for (int t4 = 0; t4 < 4; ++t4) {
            int xi = x0 + (t4 & 1);
            int yi = y0 + (t4 >> 1);
            bool valid = (xi >= 0) && (xi < 256) && (yi >= 0) && (yi < 256);
            int xc = min(max(xi, 0), 255);
            int yc = min(max(yi, 0), 255);
            dw[pl*4+t4]  = valid ? tw[t4] : 0.0f;
            dof[pl*4+t4] = yc*256 + xc;
        }
    }

    // ---- phase 1: per-wave cooperative gather, 8 lanes/point, shfl descriptors ----
    int lane  = tid & 63;
    int wbase = tid & 192;            // wave's first point in block
    int g8 = lane >> 3, sub = lane & 7;
    int c0 = sub * 4;
    size_t pbase = (size_t)(b*3) * PLANE_ELEMS;
    const float inv3 = 1.0f/3.0f;
    #pragma unroll 2
    for (int it = 0; it < 8; ++it) {
        int pw = it*8 + g8;           // source lane within wave
        int pp = wbase + pw;          // point within block
        float a0=0.f, a1=0.f, a2=0.f, a3=0.f;
        #pragma unroll
        for (int t = 0; t < 12; ++t) {
            float wv = __shfl(dw[t],  pw);
            int   tix = __shfl(dof[t], pw);
            int pl = t >> 2;
            const float4 v = *reinterpret_cast<const float4*>(
                planesT + pbase + (size_t)pl*PLANE_ELEMS + (size_t)tix*32 + c0);
            a0 = fmaf(wv, v.x, a0);
            a1 = fmaf(wv, v.y, a1);
            a2 = fmaf(wv, v.z, a2);
            a3 = fmaf(wv, v.w, a3);
        }
        featT[(c0+0)*257 + pp] = a0*inv3;
        featT[(c0+1)*257 + pp] = a1*inv3;
        featT[(c0+2)*257 + pp] = a2*inv3;
        featT[(c0+3)*257 + pp] = a3*inv3;
    }
    __syncthreads();

    // ---- phase 2: MLP (w1/w2 wave-uniform -> scalar loads) ----
    float h[64];
    #pragma unroll
    for (int j = 0; j < 64; ++j) h[j] = b1[j];
    for (int k = 0; k < 32; ++k) {
        float xk = featT[k*257 + tid];
        #pragma unroll
        for (int j = 0; j < 64; ++j) h[j] = fmaf(xk, w1[k*64 + j], h[j]);
    }
    #pragma unroll
    for (int j = 0; j < 64; ++j) h[j] = softplusf(h[j]);
    float o0 = b2[0], o1 = b2[1], o2 = b2[2], o3 = b2[3];
    for (int j = 0; j < 64; ++j) {
        float hv = h[j];
        o0 = fmaf(hv, w2[j*4+0], o0);
        o1 = fmaf(hv, w2[j*4+1], o1);
        o2 = fmaf(hv, w2[j*4+2], o2);
        o3 = fmaf(hv, w2[j*4+3], o3);
    }
    float sigma = 10.0f * softplusf(-10.0f * o0);
    float r0 = sigmoidf(o1)*1.002f - 0.001f;
    float r1 = sigmoidf(o2)*1.002f - 0.001f;
    float r2 = sigmoidf(o3)*1.002f - 0.001f;
    int slot = rid*96 + (mode ? 48 + s : s);
    colors[(size_t)slot*3+0] = r0;
    colors[(size_t)slot*3+1] = r1;
    colors[(size_t)slot*3+2] = r2;
    sigmas[slot] = sigma;
}

// K2: per-ray coarse weights -> blurred pdf -> inverse-CDF fine depths.
// 64 rays/block so all 256 CUs participate.
__global__ __launch_bounds__(64) void k_importance(
    const float* __restrict__ orig, const float* __restrict__ sigmas,
    float* __restrict__ dfine)
{
    __shared__ float tile[64*49];
    int t  = threadIdx.x;
    int r0 = blockIdx.x * 64;
    for (int it = 0; it < 48; ++it) {           // stage sigma coalesced
        int l  = it*64 + t;
        int ri = l / 48;
        int i  = l - ri*48;
        tile[ri*49 + i] = sigmas[(size_t)(r0+ri)*96 + i];
    }
    __syncthreads();
    int rid = r0 + t;
    float ox = orig[rid*3+0], oy = orig[rid*3+1], oz = orig[rid*3+2];
    float cam = sqrtf(ox*ox + oy*oy + oz*oz);

    float w[47];
    float T = 1.0f;
    float sp_ = tile[t*49 + 0];
    float dprev = coarse_depth(cam, 0);
    #pragma unroll
    for (int i = 0; i < 47; ++i) {
        float sc = tile[t*49 + i + 1];
        float dnext = coarse_depth(cam, i+1);
        float delta = dnext - dprev;
        float dm = 0.5f*(sp_ + sc);
        float a = 1.0f - __expf(-delta*dm);
        w[i] = a * T;
        T *= (1.0f - a + 1e-10f);
        sp_ = sc; dprev = dnext;
    }
    float Ssum = 0.0f;
    #pragma unroll
    for (int m = 0; m < 45; ++m) {
        float wm1 = fmaxf(w[m],   w[m+1]);
        float wm2 = fmaxf(w[m+1], w[m+2]);
        float wq = (0.5f*(wm1 + wm2) + 0.01f) + 1e-5f;
        tile[t*49 + m] = wq;
        Ssum += wq;
    }
    int idx = 1;
    float cprev = 0.0f;
    float ccur  = tile[t*49 + 0] / Ssum;        // cdf[1]
    for (int k = 0; k < 48; ++k) {
        float u = (float)k * (1.0f/47.0f);
        while (idx < 46 && ccur <= u) {
            cprev = ccur;
            idx++;
            if (idx < 46) ccur += tile[t*49 + (idx-1)] / Ssum;
        }
        int below = idx - 1;
        int above = min(idx, 45);
        float cb = cprev;
        float ca = (idx < 46) ? ccur : cprev;
        float bb = 0.5f*(coarse_depth(cam, below) + coarse_depth(cam, below+1));
        float ba = 0.5f*(coarse_depth(cam, above) + coarse_depth(cam, above+1));
        float d_ = ca - cb;
        float den = (d_ < 1e-5f) ? 1.0f : d_;
        dfine[(size_t)rid*48 + k] = bb + (u - cb)/den * (ba - bb);
    }
}

// K4: stable merge + final ray march. 32 rays/block, all sample data staged
// coalesced into LDS first (the merge's reads are data-dependent/scattered).
__global__ __launch_bounds__(64) void k_final(
    const float* __restrict__ orig,
    const float* __restrict__ colors, const float* __restrict__ sigmas,
    const float* __restrict__ dfine, float* __restrict__ out)
{
    __shared__ float scol[32*289];
    __shared__ float ssig[32*97];
    __shared__ float sdf [32*49];
    int t  = threadIdx.x;
    int r0 = blockIdx.x * 32;

    // stage colors: 32 rays * 288 floats, contiguous in global
    {
        const float4* src = reinterpret_cast<const float4*>(colors + (size_t)r0*288);
        for (int q = t; q < 2304; q += 64) {
            float4 v = src[q];
            int e = q*4, row = e/288, col = e - row*288;
            scol[row*289+col+0] = v.x; scol[row*289+col+1] = v.y;
            scol[row*289+col+2] = v.z; scol[row*289+col+3] = v.w;
        }
    }
    {
        const float4* src = reinterpret_cast<const float4*>(sigmas + (size_t)r0*96);
        for (int q = t; q < 768; q += 64) {
            float4 v = src[q];
            int e = q*4, row = e/96, col = e - row*96;
            ssig[row*97+col+0] = v.x; ssig[row*97+col+1] = v.y;
            ssig[row*97+col+2] = v.z; ssig[row*97+col+3] = v.w;
        }
    }
    {
        const float4* src = reinterpret_cast<const float4*>(dfine + (size_t)r0*48);
        for (int q = t; q < 384; q += 64) {
            float4 v = src[q];
            int e = q*4, row = e/48, col = e - row*48;
            sdf[row*49+col+0] = v.x; sdf[row*49+col+1] = v.y;
            sdf[row*49+col+2] = v.z; sdf[row*49+col+3] = v.w;
        }
    }
    __syncthreads();
    if (t >= 32) return;

    int rid = r0 + t;
    float ox = orig[rid*3+0], oy = orig[rid*3+1], oz = orig[rid*3+2];
    float cam = sqrtf(ox*ox + oy*oy + oz*oz);
    int i = 0, j = 0;
    float T = 1.0f, rgb0=0.f, rgb1=0.f, rgb2=0.f, dep=0.f, wsum=0.f;
    float dprev=0.f, sprev=0.f, cp0=0.f, cp1=0.f, cp2=0.f;
    for (int m = 0; m < 96; ++m) {
        float dc = (i < 48) ? coarse_depth(cam, i) : 3.4e38f;
        float df = (j < 48) ? sdf[t*49 + j] : 3.4e38f;
        bool takec = dc <= df;                  // stable: coarse wins ties
        int slot = takec ? i : 48 + j;
        float dcur = takec ? dc : df;
        if (takec) ++i; else ++j;
        float sc = ssig[t*97 + slot];
        float c0 = scol[t*289 + slot*3+0];
        float c1 = scol[t*289 + slot*3+1];
        float c2 = scol[t*289 + slot*3+2];
        if (m > 0) {
            float delta = dcur - dprev;
            float dm = 0.5f*(sprev + sc);
            float zm = 0.5f*(dprev + dcur);
            float a = 1.0f - __expf(-delta*dm);
            float wgt = a * T;
            T *= (1.0f - a + 1e-10f);
            rgb0 += wgt*0.5f*(cp0 + c0);
            rgb1 += wgt*0.5f*(cp1 + c1);
            rgb2 += wgt*0.5f*(cp2 + c2);
            dep  += wgt*zm;
            wsum += wgt;
        }
        dprev = dcur; sprev = sc; cp0 = c0; cp1 = c1; cp2 = c2;
    }
    out[rid*3+0] = rgb0;
    out[rid*3+1] = rgb1;
    out[rid*3+2] = rgb2;
    out[16384*3 + rid] = dep;
    out[16384*4 + rid] = wsum;
}

extern "C" void kernel_launch(void* const* d_in, const int* in_sizes, int n_in,
                              void* d_out, int out_size, void* d_ws, size_t ws_size,
                              hipStream_t stream)
{
    const float* planes = (const float*)d_in[0];
    const float* orig   = (const float*)d_in[1];
    const float* dirs   = (const float*)d_in[2];
    const float* w1     = (const float*)d_in[3];
    const float* b1     = (const float*)d_in[4];
    const float* w2     = (const float*)d_in[5];
    const float* b2     = (const float*)d_in[6];
    float* out = (float*)d_out;

    float* ws = (float*)d_ws;
    size_t n_sig = (size_t)NB*NR*96;     // 1,572,864
    size_t n_col = n_sig*3;              // 4,718,592
    size_t n_df  = (size_t)NB*NR*48;     //   786,432
    float* sig     = ws;
    float* col     = sig + n_sig;
    float* dfin    = col + n_col;
    float* planesT = dfin + n_df;

    k_transpose<<<12*256, 256, 0, stream>>>(planes, planesT);
    k_sample_mlp<<<3072, 256, 0, stream>>>(planesT, orig, dirs,
                                           w1, b1, w2, b2, dfin, col, sig, 0);
    k_importance<<<256, 64, 0, stream>>>(orig, sig, dfin);
    k_sample_mlp<<<3072, 256, 0, stream>>>(planesT, orig, dirs,
                                           w1, b1, w2, b2, dfin, col, sig, 1);
    k_final<<<512, 64, 0, stream>>>(orig, col, sig, dfin, out);
}

// Round 3
// 507.476 us; speedup vs baseline: 1.5397x; 1.0566x over previous
//
#include <hip/hip_runtime.h>
#include <hip/hip_fp16.h>
#include <math.h>

#define NB 4
#define NR 4096
#define NS 48
#define PLANE_ELEMS (65536*32)   // H*W*C per (b,plane)

__device__ __forceinline__ float coarse_depth(float cam, int i) {
    float nearv = cam - 0.5f;
    float farv  = cam + 0.5f;
    float t = ((float)i + 0.5f) / 48.0f;
    return nearv + (farv - nearv) * t;
}
__device__ __forceinline__ float softplusf(float x) {
    return fmaxf(x, 0.0f) + __logf(1.0f + __expf(-fabsf(x)));
}
__device__ __forceinline__ float sigmoidf(float x) {
    return 1.0f / (1.0f + __expf(-x));
}

// K0: transpose planes [bp][C][H][W] -> [bp][H][W][C], LDS-free.
// 8 lanes/texel: lane sub loads 4 channels (strided, coalesced across x),
// stores one float4 -> contiguous 1KB/wave writes.
__global__ __launch_bounds__(256) void k_transpose(const float* __restrict__ src,
                                                   float* __restrict__ dst) {
    int bp = blockIdx.x >> 8;
    int y  = blockIdx.x & 255;
    int t  = threadIdx.x;
    int sub = t & 7, c0 = sub * 4;
    int g   = t >> 3;                 // 32 texels per pass
    const float* s = src + (size_t)bp*PLANE_ELEMS + (size_t)y*256;
    float* d = dst + ((size_t)bp*65536 + (size_t)y*256)*32;
    #pragma unroll
    for (int p = 0; p < 8; ++p) {
        int x = p*32 + g;
        float4 v;
        v.x = s[(size_t)(c0+0)*65536 + x];
        v.y = s[(size_t)(c0+1)*65536 + x];
        v.z = s[(size_t)(c0+2)*65536 + x];
        v.w = s[(size_t)(c0+3)*65536 + x];
        *reinterpret_cast<float4*>(d + (size_t)x*32 + c0) = v;
    }
}

// K1/K3: plane sampling + decoder MLP. One block = 256 points.
// Tap descriptors packed (f16 weight <<16 | u16 texel) in LDS -> gather lanes
// read them via broadcast ds_read_b64 (no bpermute dependency chain), then
// issue 6-wide batches of global float4 loads. LDS 30.9KB -> 5 blocks/CU.
__global__ __launch_bounds__(256, 5) void k_sample_mlp(
    const float* __restrict__ planesT,
    const float* __restrict__ orig, const float* __restrict__ dirs,
    const float* __restrict__ w1, const float* __restrict__ b1,
    const float* __restrict__ w2, const float* __restrict__ b2,
    const float* __restrict__ dfine,
    float* __restrict__ colors, float* __restrict__ sigmas,
    int mode)
{
    __shared__ unsigned desc[256*14];   // [pt][14]: 12 packed taps + 2 pad
    __shared__ unsigned featT[16*260];  // [c-pair][pt], f16x2; stride 260 -> 2-way-free

    int tid = threadIdx.x;
    int pid = blockIdx.x * 256 + tid;
    int rid = pid / 48;
    int s   = pid - rid*48;
    int b   = rid >> 12;

    // ---- phase 0: this thread's point -> 12 packed tap descriptors ----
    float ox = orig[rid*3+0], oy = orig[rid*3+1], oz = orig[rid*3+2];
    float dxv = dirs[rid*3+0], dyv = dirs[rid*3+1], dzv = dirs[rid*3+2];
    float depth;
    if (mode == 0) {
        float cam = sqrtf(ox*ox + oy*oy + oz*oz);
        depth = coarse_depth(cam, s);
    } else {
        depth = dfine[(size_t)rid*48 + s];
    }
    float cx = ox + depth*dxv;
    float cy = oy + depth*dyv;
    float cz = oz + depth*dzv;
    float us[3] = {cx, cz, cy};   // p0 (x,y), p1 (z,x), p2 (y,z)
    float vs[3] = {cy, cx, cz};
    unsigned dpk[12];
    #pragma unroll
    for (int pl = 0; pl < 3; ++pl) {
        float xg = (us[pl] + 1.0f) * 0.5f * 256.0f - 0.5f;
        float yg = (vs[pl] + 1.0f) * 0.5f * 256.0f - 0.5f;
        float x0f = floorf(xg), y0f = floorf(yg);
        float wx = xg - x0f, wy = yg - y0f;
        int x0 = (int)x0f, y0 = (int)y0f;
        float tw[4] = {(1.0f-wx)*(1.0f-wy), wx*(1.0f-wy), (1.0f-wx)*wy, wx*wy};
        #pragma unroll
        for (int t4 = 0; t4 < 4; ++t4) {
            int xi = x0 + (t4 & 1);
            int yi = y0 + (t4 >> 1);
            bool valid = (xi >= 0) && (xi < 256) && (yi >= 0) && (yi < 256);
            int xc = min(max(xi, 0), 255);
            int yc = min(max(yi, 0), 255);
            float wv = valid ? tw[t4] : 0.0f;
            dpk[pl*4+t4] = ((unsigned)__half_as_ushort(__float2half_rn(wv)) << 16)
                         | (unsigned)(yc*256 + xc);
        }
    }
    #pragma unroll
    for (int q = 0; q < 6; ++q)
        *reinterpret_cast<uint2*>(&desc[tid*14 + 2*q]) = make_uint2(dpk[2*q], dpk[2*q+1]);
    __syncthreads();

    // ---- phase 1: per-wave gather, 8 lanes/point, batched loads ----
    int lane = tid & 63, wbase = tid & 192;
    int g8 = lane >> 3, sub = lane & 7, c0 = sub*4;
    const float* pbase = planesT + (size_t)(b*3)*PLANE_ELEMS + c0;
    const float inv3 = 1.0f/3.0f;
    #pragma unroll 2
    for (int it = 0; it < 8; ++it) {
        int pp = wbase + it*8 + g8;
        float a0=0.f, a1=0.f, a2=0.f, a3=0.f;
        #pragma unroll
        for (int h6 = 0; h6 < 2; ++h6) {
            unsigned dd[6];
            #pragma unroll
            for (int q = 0; q < 3; ++q) {
                uint2 pr = *reinterpret_cast<const uint2*>(&desc[pp*14 + h6*6 + 2*q]);
                dd[2*q] = pr.x; dd[2*q+1] = pr.y;
            }
            float4 v[6]; float wv[6];
            #pragma unroll
            for (int q = 0; q < 6; ++q) {
                int tp = h6*6 + q;
                int tix = dd[q] & 0xFFFF;
                wv[q] = __half2float(__ushort_as_half((unsigned short)(dd[q] >> 16)));
                v[q] = *reinterpret_cast<const float4*>(
                    pbase + (size_t)(tp>>2)*PLANE_ELEMS + (size_t)tix*32);
            }
            #pragma unroll
            for (int q = 0; q < 6; ++q) {
                a0 = fmaf(wv[q], v[q].x, a0);
                a1 = fmaf(wv[q], v[q].y, a1);
                a2 = fmaf(wv[q], v[q].z, a2);
                a3 = fmaf(wv[q], v[q].w, a3);
            }
        }
        a0*=inv3; a1*=inv3; a2*=inv3; a3*=inv3;
        unsigned p0 = ((unsigned)__half_as_ushort(__float2half_rn(a1))<<16)
                    |  (unsigned)__half_as_ushort(__float2half_rn(a0));
        unsigned p1 = ((unsigned)__half_as_ushort(__float2half_rn(a3))<<16)
                    |  (unsigned)__half_as_ushort(__float2half_rn(a2));
        featT[(2*sub+0)*260 + pp] = p0;   // row r holds channels 2r, 2r+1
        featT[(2*sub+1)*260 + pp] = p1;
    }
    __syncthreads();

    // ---- phase 2: MLP (w1/w2 wave-uniform -> scalar loads) ----
    float h[64];
    #pragma unroll
    for (int j = 0; j < 64; ++j) h[j] = b1[j];
    for (int k2 = 0; k2 < 16; ++k2) {
        unsigned u = featT[k2*260 + tid];
        float x0 = __half2float(__ushort_as_half((unsigned short)(u & 0xFFFFu)));
        float x1 = __half2float(__ushort_as_half((unsigned short)(u >> 16)));
        const float* w1r = w1 + (size_t)(2*k2)*64;
        #pragma unroll
        for (int j = 0; j < 64; ++j)
            h[j] = fmaf(x1, w1r[64+j], fmaf(x0, w1r[j], h[j]));
    }
    #pragma unroll
    for (int j = 0; j < 64; ++j) h[j] = softplusf(h[j]);
    float o0 = b2[0], o1 = b2[1], o2 = b2[2], o3 = b2[3];
    for (int j = 0; j < 64; ++j) {
        float hv = h[j];
        o0 = fmaf(hv, w2[j*4+0], o0);
        o1 = fmaf(hv, w2[j*4+1], o1);
        o2 = fmaf(hv, w2[j*4+2], o2);
        o3 = fmaf(hv, w2[j*4+3], o3);
    }
    float sigma = 10.0f * softplusf(-10.0f * o0);
    float r0 = sigmoidf(o1)*1.002f - 0.001f;
    float r1 = sigmoidf(o2)*1.002f - 0.001f;
    float r2 = sigmoidf(o3)*1.002f - 0.001f;
    int slot = rid*96 + (mode ? 48 + s : s);
    colors[(size_t)slot*3+0] = r0;
    colors[(size_t)slot*3+1] = r1;
    colors[(size_t)slot*3+2] = r2;
    sigmas[slot] = sigma;
}

// K2: per-ray coarse weights -> blurred pdf -> inverse-CDF fine depths.
__global__ __launch_bounds__(64) void k_importance(
    const float* __restrict__ orig, const float* __restrict__ sigmas,
    float* __restrict__ dfine)
{
    __shared__ float tile[64*49];
    int t  = threadIdx.x;
    int r0 = blockIdx.x * 64;
    for (int it = 0; it < 48; ++it) {
        int l  = it*64 + t;
        int ri = l / 48;
        int i  = l - ri*48;
        tile[ri*49 + i] = sigmas[(size_t)(r0+ri)*96 + i];
    }
    __syncthreads();
    int rid = r0 + t;
    float ox = orig[rid*3+0], oy = orig[rid*3+1], oz = orig[rid*3+2];
    float cam = sqrtf(ox*ox + oy*oy + oz*oz);

    float w[47];
    float T = 1.0f;
    float sp_ = tile[t*49 + 0];
    float dprev = coarse_depth(cam, 0);
    #pragma unroll
    for (int i = 0; i < 47; ++i) {
        float sc = tile[t*49 + i + 1];
        float dnext = coarse_depth(cam, i+1);
        float delta = dnext - dprev;
        float dm = 0.5f*(sp_ + sc);
        float a = 1.0f - __expf(-delta*dm);
        w[i] = a * T;
        T *= (1.0f - a + 1e-10f);
        sp_ = sc; dprev = dnext;
    }
    float Ssum = 0.0f;
    #pragma unroll
    for (int m = 0; m < 45; ++m) {
        float wm1 = fmaxf(w[m],   w[m+1]);
        float wm2 = fmaxf(w[m+1], w[m+2]);
        float wq = (0.5f*(wm1 + wm2) + 0.01f) + 1e-5f;
        tile[t*49 + m] = wq;
        Ssum += wq;
    }
    int idx = 1;
    float cprev = 0.0f;
    float ccur  = tile[t*49 + 0] / Ssum;
    for (int k = 0; k < 48; ++k) {
        float u = (float)k * (1.0f/47.0f);
        while (idx < 46 && ccur <= u) {
            cprev = ccur;
            idx++;
            if (idx < 46) ccur += tile[t*49 + (idx-1)] / Ssum;
        }
        int below = idx - 1;
        int above = min(idx, 45);
        float cb = cprev;
        float ca = (idx < 46) ? ccur : cprev;
        float bb = 0.5f*(coarse_depth(cam, below) + coarse_depth(cam, below+1));
        float ba = 0.5f*(coarse_depth(cam, above) + coarse_depth(cam, above+1));
        float d_ = ca - cb;
        float den = (d_ < 1e-5f) ? 1.0f : d_;
        dfine[(size_t)rid*48 + k] = bb + (u - cb)/den * (ba - bb);
    }
}

// K4: stable merge + final ray march; sample data staged coalesced into LDS.
__global__ __launch_bounds__(64) void k_final(
    const float* __restrict__ orig,
    const float* __restrict__ colors, const float* __restrict__ sigmas,
    const float* __restrict__ dfine, float* __restrict__ out)
{
    __shared__ float scol[32*289];
    __shared__ float ssig[32*97];
    __shared__ float sdf [32*49];
    int t  = threadIdx.x;
    int r0 = blockIdx.x * 32;

    {
        const float4* src = reinterpret_cast<const float4*>(colors + (size_t)r0*288);
        for (int q = t; q < 2304; q += 64) {
            float4 v = src[q];
            int e = q*4, row = e/288, col = e - row*288;
            scol[row*289+col+0] = v.x; scol[row*289+col+1] = v.y;
            scol[row*289+col+2] = v.z; scol[row*289+col+3] = v.w;
        }
    }
    {
        const float4* src = reinterpret_cast<const float4*>(sigmas + (size_t)r0*96);
        for (int q = t; q < 768; q += 64) {
            float4 v = src[q];
            int e = q*4, row = e/96, col = e - row*96;
            ssig[row*97+col+0] = v.x; ssig[row*97+col+1] = v.y;
            ssig[row*97+col+2] = v.z; ssig[row*97+col+3] = v.w;
        }
    }
    {
        const float4* src = reinterpret_cast<const float4*>(dfine + (size_t)r0*48);
        for (int q = t; q < 384; q += 64) {
            float4 v = src[q];
            int e = q*4, row = e/48, col = e - row*48;
            sdf[row*49+col+0] = v.x; sdf[row*49+col+1] = v.y;
            sdf[row*49+col+2] = v.z; sdf[row*49+col+3] = v.w;
        }
    }
    __syncthreads();
    if (t >= 32) return;

    int rid = r0 + t;
    float ox = orig[rid*3+0], oy = orig[rid*3+1], oz = orig[rid*3+2];
    float cam = sqrtf(ox*ox + oy*oy + oz*oz);
    int i = 0, j = 0;
    float T = 1.0f, rgb0=0.f, rgb1=0.f, rgb2=0.f, dep=0.f, wsum=0.f;
    float dprev=0.f, sprev=0.f, cp0=0.f, cp1=0.f, cp2=0.f;
    for (int m = 0; m < 96; ++m) {
        float dc = (i < 48) ? coarse_depth(cam, i) : 3.4e38f;
        float df = (j < 48) ? sdf[t*49 + j] : 3.4e38f;
        bool takec = dc <= df;                  // stable: coarse wins ties
        int slot = takec ? i : 48 + j;
        float dcur = takec ? dc : df;
        if (takec) ++i; else ++j;
        float sc = ssig[t*97 + slot];
        float c0 = scol[t*289 + slot*3+0];
        float c1 = scol[t*289 + slot*3+1];
        float c2 = scol[t*289 + slot*3+2];
        if (m > 0) {
            float delta = dcur - dprev;
            float dm = 0.5f*(sprev + sc);
            float zm = 0.5f*(dprev + dcur);
            float a = 1.0f - __expf(-delta*dm);
            float wgt = a * T;
            T *= (1.0f - a + 1e-10f);
            rgb0 += wgt*0.5f*(cp0 + c0);
            rgb1 += wgt*0.5f*(cp1 + c1);
            rgb2 += wgt*0.5f*(cp2 + c2);
            dep  += wgt*zm;
            wsum += wgt;
        }
        dprev = dcur; sprev = sc; cp0 = c0; cp1 = c1; cp2 = c2;
    }
    out[rid*3+0] = rgb0;
    out[rid*3+1] = rgb1;
    out[rid*3+2] = rgb2;
    out[16384*3 + rid] = dep;
    out[16384*4 + rid] = wsum;
}

extern "C" void kernel_launch(void* const* d_in, const int* in_sizes, int n_in,
                              void* d_out, int out_size, void* d_ws, size_t ws_size,
                              hipStream_t stream)
{
    const float* planes = (const float*)d_in[0];
    const float* orig   = (const float*)d_in[1];
    const float* dirs   = (const float*)d_in[2];
    const float* w1     = (const float*)d_in[3];
    const float* b1     = (const float*)d_in[4];
    const float* w2     = (const float*)d_in[5];
    const float* b2     = (const float*)d_in[6];
    float* out = (float*)d_out;

    float* ws = (float*)d_ws;
    size_t n_sig = (size_t)NB*NR*96;
    size_t n_col = n_sig*3;
    size_t n_df  = (size_t)NB*NR*48;
    float* sig     = ws;
    float* col     = sig + n_sig;
    float* dfin    = col + n_col;
    float* planesT = dfin + n_df;

    k_transpose<<<12*256, 256, 0, stream>>>(planes, planesT);
    k_sample_mlp<<<3072, 256, 0, stream>>>(planesT, orig, dirs,
                                           w1, b1, w2, b2, dfin, col, sig, 0);
    k_importance<<<256, 64, 0, stream>>>(orig, sig, dfin);
    k_sample_mlp<<<3072, 256, 0, stream>>>(planesT, orig, dirs,
                                           w1, b1, w2, b2, dfin, col, sig, 1);
    k_final<<<512, 64, 0, stream>>>(orig, col, sig, dfin, out);
}

// Round 4
// 382.770 us; speedup vs baseline: 2.0414x; 1.3258x over previous
//
#include <hip/hip_runtime.h>
#include <hip/hip_fp16.h>
#include <math.h>

#define NB 4
#define NR 4096
#define NS 48
#define PLANE_ELEMS (65536*32)   // H*W*C per (b,plane) (elements)

typedef _Float16 half2v __attribute__((ext_vector_type(2)));

__device__ __forceinline__ float coarse_depth(float cam, int i) {
    float nearv = cam - 0.5f;
    float farv  = cam + 0.5f;
    float t = ((float)i + 0.5f) / 48.0f;
    return nearv + (farv - nearv) * t;
}
__device__ __forceinline__ float softplusf(float x) {
    return fmaxf(x, 0.0f) + __logf(1.0f + __expf(-fabsf(x)));
}
__device__ __forceinline__ float sigmoidf(float x) {
    return 1.0f / (1.0f + __expf(-x));
}
// f32 += dot(half2, half2) — hardware v_dot2_f32_f16 when available
__device__ __forceinline__ float fdot2f(unsigned a, unsigned b, float c) {
#if defined(__has_builtin) && __has_builtin(__builtin_amdgcn_fdot2)
    half2v av, bv;
    __builtin_memcpy(&av, &a, 4);
    __builtin_memcpy(&bv, &b, 4);
    return __builtin_amdgcn_fdot2(av, bv, c, false);
#else
    __half2 ah, bh;
    __builtin_memcpy(&ah, &a, 4);
    __builtin_memcpy(&bh, &b, 4);
    float2 af = __half22float2(ah), bf = __half22float2(bh);
    return fmaf(af.x, bf.x, fmaf(af.y, bf.y, c));
#endif
}

// K0: transpose planes [bp][C][H][W] f32 -> [bp][H][W][C] f16 (64B/texel).
// Coalesced 1KB reads per channel, LDS ushort tile, contiguous 16KB writes.
// Block 3072 packs w1 f32[32][64] -> half2[16][64].
__global__ __launch_bounds__(256) void k_transpose(const float* __restrict__ src,
                                                   __half* __restrict__ dst,
                                                   const float* __restrict__ w1,
                                                   unsigned* __restrict__ w1h) {
    if (blockIdx.x == 3072) {
        int t = threadIdx.x;
        for (int q = t; q < 1024; q += 256) {
            int k2 = q >> 6, j = q & 63;
            __half lo = __float2half_rn(w1[(2*k2+0)*64 + j]);
            __half hi = __float2half_rn(w1[(2*k2+1)*64 + j]);
            w1h[q] = (unsigned)__half_as_ushort(lo)
                   | ((unsigned)__half_as_ushort(hi) << 16);
        }
        return;
    }
    __shared__ unsigned short tile[256*33];
    int bp = blockIdx.x >> 8;
    int y  = blockIdx.x & 255;
    int t  = threadIdx.x;
    const float* s = src + (size_t)bp*PLANE_ELEMS + (size_t)y*256;
    #pragma unroll
    for (int c = 0; c < 32; ++c)
        tile[t*33 + c] = __half_as_ushort(__float2half_rn(s[(size_t)c*65536 + t]));
    __syncthreads();
    unsigned* d = reinterpret_cast<unsigned*>(dst + ((size_t)bp*65536 + (size_t)y*256)*32);
    #pragma unroll
    for (int it = 0; it < 16; ++it) {
        int q = it*256 + t;            // 4096 uints, contiguous
        int x = q >> 4, c2 = q & 15;
        unsigned lo = tile[x*33 + 2*c2];
        unsigned hi = tile[x*33 + 2*c2 + 1];
        d[q] = lo | (hi << 16);
    }
}

// K1/K3: plane sampling + decoder MLP. One block = 256 points.
// f16 planes: 8 lanes/point, 8B/tap/lane, __hfma2 accumulate; w1 GEMV via
// v_dot2_f32_f16 against half2-packed feat. LDS 28.7KB -> 5 blocks/CU.
__global__ __launch_bounds__(256, 5) void k_sample_mlp(
    const __half* __restrict__ planesT,
    const float* __restrict__ orig, const float* __restrict__ dirs,
    const unsigned* __restrict__ w1h, const float* __restrict__ b1,
    const float* __restrict__ w2, const float* __restrict__ b2,
    const float* __restrict__ dfine,
    float* __restrict__ colors, float* __restrict__ sigmas,
    int mode)
{
    __shared__ unsigned desc[256*12];   // [pt][12]: f16 weight<<16 | u16 texel
    __shared__ unsigned featT[16*257];  // [c-pair][pt], f16x2

    int tid = threadIdx.x;
    int pid = blockIdx.x * 256 + tid;
    int rid = pid / 48;
    int s   = pid - rid*48;
    int b   = rid >> 12;

    // ---- phase 0: 12 packed tap descriptors for this thread's point ----
    float ox = orig[rid*3+0], oy = orig[rid*3+1], oz = orig[rid*3+2];
    float dxv = dirs[rid*3+0], dyv = dirs[rid*3+1], dzv = dirs[rid*3+2];
    float depth;
    if (mode == 0) {
        float cam = sqrtf(ox*ox + oy*oy + oz*oz);
        depth = coarse_depth(cam, s);
    } else {
        depth = dfine[(size_t)rid*48 + s];
    }
    float cx = ox + depth*dxv;
    float cy = oy + depth*dyv;
    float cz = oz + depth*dzv;
    float us[3] = {cx, cz, cy};   // p0 (x,y), p1 (z,x), p2 (y,z)
    float vs[3] = {cy, cx, cz};
    unsigned dpk[12];
    #pragma unroll
    for (int pl = 0; pl < 3; ++pl) {
        float xg = (us[pl] + 1.0f) * 0.5f * 256.0f - 0.5f;
        float yg = (vs[pl] + 1.0f) * 0.5f * 256.0f - 0.5f;
        float x0f = floorf(xg), y0f = floorf(yg);
        float wx = xg - x0f, wy = yg - y0f;
        int x0 = (int)x0f, y0 = (int)y0f;
        float tw[4] = {(1.0f-wx)*(1.0f-wy), wx*(1.0f-wy), (1.0f-wx)*wy, wx*wy};
        #pragma unroll
        for (int t4 = 0; t4 < 4; ++t4) {
            int xi = x0 + (t4 & 1);
            int yi = y0 + (t4 >> 1);
            bool valid = (xi >= 0) && (xi < 256) && (yi >= 0) && (yi < 256);
            int xc = min(max(xi, 0), 255);
            int yc = min(max(yi, 0), 255);
            float wv = valid ? tw[t4] : 0.0f;
            dpk[pl*4+t4] = ((unsigned)__half_as_ushort(__float2half_rn(wv)) << 16)
                         | (unsigned)(yc*256 + xc);
        }
    }
    #pragma unroll
    for (int q = 0; q < 6; ++q)
        *reinterpret_cast<uint2*>(&desc[tid*12 + 2*q]) = make_uint2(dpk[2*q], dpk[2*q+1]);
    __syncthreads();

    // ---- phase 1: per-wave gather, 8 lanes/point, 8B taps, hfma2 ----
    int lane = tid & 63, wbase = tid & 192;
    int g8 = lane >> 3, sub = lane & 7, c0 = sub*4;
    const __half* pbase = planesT + (size_t)(b*3)*PLANE_ELEMS + c0;
    const __half2 inv3h = __float2half2_rn(1.0f/3.0f);
    #pragma unroll 2
    for (int it = 0; it < 8; ++it) {
        int pp = wbase + it*8 + g8;
        __half2 a01 = __float2half2_rn(0.0f);
        __half2 a23 = __float2half2_rn(0.0f);
        #pragma unroll
        for (int h6 = 0; h6 < 2; ++h6) {
            unsigned dd[6];
            #pragma unroll
            for (int q = 0; q < 3; ++q) {
                uint2 pr = *reinterpret_cast<const uint2*>(&desc[pp*12 + h6*6 + 2*q]);
                dd[2*q] = pr.x; dd[2*q+1] = pr.y;
            }
            uint2 v[6]; __half2 wv[6];
            #pragma unroll
            for (int q = 0; q < 6; ++q) {
                int tp = h6*6 + q;
                int tix = dd[q] & 0xFFFF;
                wv[q] = __half2half2(__ushort_as_half((unsigned short)(dd[q] >> 16)));
                v[q] = *reinterpret_cast<const uint2*>(
                    pbase + (size_t)(tp>>2)*PLANE_ELEMS + ((size_t)tix << 5));
            }
            #pragma unroll
            for (int q = 0; q < 6; ++q) {
                __half2 v01, v23;
                __builtin_memcpy(&v01, &v[q].x, 4);
                __builtin_memcpy(&v23, &v[q].y, 4);
                a01 = __hfma2(wv[q], v01, a01);
                a23 = __hfma2(wv[q], v23, a23);
            }
        }
        a01 = __hmul2(a01, inv3h);
        a23 = __hmul2(a23, inv3h);
        unsigned u01, u23;
        __builtin_memcpy(&u01, &a01, 4);
        __builtin_memcpy(&u23, &a23, 4);
        featT[(2*sub+0)*257 + pp] = u01;   // row r = channels 2r,2r+1
        featT[(2*sub+1)*257 + pp] = u23;
    }
    __syncthreads();

    // ---- phase 2: MLP. w1: 1024 v_dot2_f32_f16; w1h/w2 wave-uniform ----
    float h[64];
    #pragma unroll
    for (int j = 0; j < 64; ++j) h[j] = b1[j];
    for (int k2 = 0; k2 < 16; ++k2) {
        unsigned x2 = featT[k2*257 + tid];
        const unsigned* wrow = w1h + k2*64;
        #pragma unroll
        for (int j = 0; j < 64; ++j)
            h[j] = fdot2f(x2, wrow[j], h[j]);
    }
    #pragma unroll
    for (int j = 0; j < 64; ++j) h[j] = softplusf(h[j]);
    float o0 = b2[0], o1 = b2[1], o2 = b2[2], o3 = b2[3];
    for (int j = 0; j < 64; ++j) {
        float hv = h[j];
        o0 = fmaf(hv, w2[j*4+0], o0);
        o1 = fmaf(hv, w2[j*4+1], o1);
        o2 = fmaf(hv, w2[j*4+2], o2);
        o3 = fmaf(hv, w2[j*4+3], o3);
    }
    float sigma = 10.0f * softplusf(-10.0f * o0);
    float r0 = sigmoidf(o1)*1.002f - 0.001f;
    float r1 = sigmoidf(o2)*1.002f - 0.001f;
    float r2 = sigmoidf(o3)*1.002f - 0.001f;
    int slot = rid*96 + (mode ? 48 + s : s);
    colors[(size_t)slot*3+0] = r0;
    colors[(size_t)slot*3+1] = r1;
    colors[(size_t)slot*3+2] = r2;
    sigmas[slot] = sigma;
}

// K2: per-ray coarse weights -> blurred pdf -> inverse-CDF fine depths.
__global__ __launch_bounds__(64) void k_importance(
    const float* __restrict__ orig, const float* __restrict__ sigmas,
    float* __restrict__ dfine)
{
    __shared__ float tile[64*49];
    int t  = threadIdx.x;
    int r0 = blockIdx.x * 64;
    for (int it = 0; it < 48; ++it) {
        int l  = it*64 + t;
        int ri = l / 48;
        int i  = l - ri*48;
        tile[ri*49 + i] = sigmas[(size_t)(r0+ri)*96 + i];
    }
    __syncthreads();
    int rid = r0 + t;
    float ox = orig[rid*3+0], oy = orig[rid*3+1], oz = orig[rid*3+2];
    float cam = sqrtf(ox*ox + oy*oy + oz*oz);

    float w[47];
    float T = 1.0f;
    float sp_ = tile[t*49 + 0];
    float dprev = coarse_depth(cam, 0);
    #pragma unroll
    for (int i = 0; i < 47; ++i) {
        float sc = tile[t*49 + i + 1];
        float dnext = coarse_depth(cam, i+1);
        float delta = dnext - dprev;
        float dm = 0.5f*(sp_ + sc);
        float a = 1.0f - __expf(-delta*dm);
        w[i] = a * T;
        T *= (1.0f - a + 1e-10f);
        sp_ = sc; dprev = dnext;
    }
    float Ssum = 0.0f;
    #pragma unroll
    for (int m = 0; m < 45; ++m) {
        float wm1 = fmaxf(w[m],   w[m+1]);
        float wm2 = fmaxf(w[m+1], w[m+2]);
        float wq = (0.5f*(wm1 + wm2) + 0.01f) + 1e-5f;
        tile[t*49 + m] = wq;
        Ssum += wq;
    }
    int idx = 1;
    float cprev = 0.0f;
    float ccur  = tile[t*49 + 0] / Ssum;
    for (int k = 0; k < 48; ++k) {
        float u = (float)k * (1.0f/47.0f);
        while (idx < 46 && ccur <= u) {
            cprev = ccur;
            idx++;
            if (idx < 46) ccur += tile[t*49 + (idx-1)] / Ssum;
        }
        int below = idx - 1;
        int above = min(idx, 45);
        float cb = cprev;
        float ca = (idx < 46) ? ccur : cprev;
        float bb = 0.5f*(coarse_depth(cam, below) + coarse_depth(cam, below+1));
        float ba = 0.5f*(coarse_depth(cam, above) + coarse_depth(cam, above+1));
        float d_ = ca - cb;
        float den = (d_ < 1e-5f) ? 1.0f : d_;
        dfine[(size_t)rid*48 + k] = bb + (u - cb)/den * (ba - bb);
    }
}

// K4: stable merge + final ray march; sample data staged coalesced into LDS.
__global__ __launch_bounds__(64) void k_final(
    const float* __restrict__ orig,
    const float* __restrict__ colors, const float* __restrict__ sigmas,
    const float* __restrict__ dfine, float* __restrict__ out)
{
    __shared__ float scol[32*289];
    __shared__ float ssig[32*97];
    __shared__ float sdf [32*49];
    int t  = threadIdx.x;
    int r0 = blockIdx.x * 32;

    {
        const float4* src = reinterpret_cast<const float4*>(colors + (size_t)r0*288);
        for (int q = t; q < 2304; q += 64) {
            float4 v = src[q];
            int e = q*4, row = e/288, col = e - row*288;
            scol[row*289+col+0] = v.x; scol[row*289+col+1] = v.y;
            scol[row*289+col+2] = v.z; scol[row*289+col+3] = v.w;
        }
    }
    {
        const float4* src = reinterpret_cast<const float4*>(sigmas + (size_t)r0*96);
        for (int q = t; q < 768; q += 64) {
            float4 v = src[q];
            int e = q*4, row = e/96, col = e - row*96;
            ssig[row*97+col+0] = v.x; ssig[row*97+col+1] = v.y;
            ssig[row*97+col+2] = v.z; ssig[row*97+col+3] = v.w;
        }
    }
    {
        const float4* src = reinterpret_cast<const float4*>(dfine + (size_t)r0*48);
        for (int q = t; q < 384; q += 64) {
            float4 v = src[q];
            int e = q*4, row = e/48, col = e - row*48;
            sdf[row*49+col+0] = v.x; sdf[row*49+col+1] = v.y;
            sdf[row*49+col+2] = v.z; sdf[row*49+col+3] = v.w;
        }
    }
    __syncthreads();
    if (t >= 32) return;

    int rid = r0 + t;
    float ox = orig[rid*3+0], oy = orig[rid*3+1], oz = orig[rid*3+2];
    float cam = sqrtf(ox*ox + oy*oy + oz*oz);
    int i = 0, j = 0;
    float T = 1.0f, rgb0=0.f, rgb1=0.f, rgb2=0.f, dep=0.f, wsum=0.f;
    float dprev=0.f, sprev=0.f, cp0=0.f, cp1=0.f, cp2=0.f;
    for (int m = 0; m < 96; ++m) {
        float dc = (i < 48) ? coarse_depth(cam, i) : 3.4e38f;
        float df = (j < 48) ? sdf[t*49 + j] : 3.4e38f;
        bool takec = dc <= df;                  // stable: coarse wins ties
        int slot = takec ? i : 48 + j;
        float dcur = takec ? dc : df;
        if (takec) ++i; else ++j;
        float sc = ssig[t*97 + slot];
        float c0 = scol[t*289 + slot*3+0];
        float c1 = scol[t*289 + slot*3+1];
        float c2 = scol[t*289 + slot*3+2];
        if (m > 0) {
            float delta = dcur - dprev;
            float dm = 0.5f*(sprev + sc);
            float zm = 0.5f*(dprev + dcur);
            float a = 1.0f - __expf(-delta*dm);
            float wgt = a * T;
            T *= (1.0f - a + 1e-10f);
            rgb0 += wgt*0.5f*(cp0 + c0);
            rgb1 += wgt*0.5f*(cp1 + c1);
            rgb2 += wgt*0.5f*(cp2 + c2);
            dep  += wgt*zm;
            wsum += wgt;
        }
        dprev = dcur; sprev = sc; cp0 = c0; cp1 = c1; cp2 = c2;
    }
    out[rid*3+0] = rgb0;
    out[rid*3+1] = rgb1;
    out[rid*3+2] = rgb2;
    out[16384*3 + rid] = dep;
    out[16384*4 + rid] = wsum;
}

extern "C" void kernel_launch(void* const* d_in, const int* in_sizes, int n_in,
                              void* d_out, int out_size, void* d_ws, size_t ws_size,
                              hipStream_t stream)
{
    const float* planes = (const float*)d_in[0];
    const float* orig   = (const float*)d_in[1];
    const float* dirs   = (const float*)d_in[2];
    const float* w1     = (const float*)d_in[3];
    const float* b1     = (const float*)d_in[4];
    const float* w2     = (const float*)d_in[5];
    const float* b2     = (const float*)d_in[6];
    float* out = (float*)d_out;

    float* ws = (float*)d_ws;
    size_t n_sig = (size_t)NB*NR*96;
    size_t n_col = n_sig*3;
    size_t n_df  = (size_t)NB*NR*48;
    float*  sig     = ws;
    float*  col     = sig + n_sig;
    float*  dfin    = col + n_col;
    __half* planesT = (__half*)(dfin + n_df);              // 8B-aligned
    unsigned* w1h   = (unsigned*)(planesT + (size_t)12*PLANE_ELEMS);

    k_transpose<<<3073, 256, 0, stream>>>(planes, planesT, w1, w1h);
    k_sample_mlp<<<3072, 256, 0, stream>>>(planesT, orig, dirs,
                                           w1h, b1, w2, b2, dfin, col, sig, 0);
    k_importance<<<256, 64, 0, stream>>>(orig, sig, dfin);
    k_sample_mlp<<<3072, 256, 0, stream>>>(planesT, orig, dirs,
                                           w1h, b1, w2, b2, dfin, col, sig, 1);
    k_final<<<512, 64, 0, stream>>>(orig, col, sig, dfin, out);
}

// Round 5
// 337.142 us; speedup vs baseline: 2.3176x; 1.1353x over previous
//
#include <hip/hip_runtime.h>
#include <hip/hip_fp16.h>
#include <math.h>

#define NB 4
#define NR 4096
#define NS 48
#define PLANE_ELEMS (65536*32)   // H*W*C per (b,plane) (elements)

typedef _Float16 f16x8 __attribute__((ext_vector_type(8)));
typedef float    f32x4 __attribute__((ext_vector_type(4)));

__device__ __forceinline__ float coarse_depth(float cam, int i) {
    float nearv = cam - 0.5f;
    float farv  = cam + 0.5f;
    float t = ((float)i + 0.5f) / 48.0f;
    return nearv + (farv - nearv) * t;
}
__device__ __forceinline__ float softplusf(float x) {
    return fmaxf(x, 0.0f) + __logf(1.0f + __expf(-fabsf(x)));
}
__device__ __forceinline__ float sigmoidf(float x) {
    return 1.0f / (1.0f + __expf(-x));
}

// K0: transpose planes [bp][C][H][W] f32 -> [bp][H][W][C] f16 (64B/texel).
// Block 3072 packs w1 into MFMA A-fragment layout:
// w1frag[(ht*64+lane)*4+q] = half2( w1[k0][ht*16+m], w1[k0+1][ht*16+m] ),
// k0 = (lane>>4)*8 + 2q, m = lane&15  (A[m][k=quad*8+j], j = reg*2+half).
__global__ __launch_bounds__(256) void k_transpose(const float* __restrict__ src,
                                                   __half* __restrict__ dst,
                                                   const float* __restrict__ w1,
                                                   unsigned* __restrict__ w1frag) {
    if (blockIdx.x == 3072) {
        int t = threadIdx.x;
        for (int f = t; f < 1024; f += 256) {
            int ht = f >> 8, rem = f & 255, lane = rem >> 2, qq = rem & 3;
            int quad = lane >> 4, m = lane & 15;
            int k0 = quad*8 + 2*qq;
            __half lo = __float2half_rn(w1[(k0+0)*64 + ht*16 + m]);
            __half hi = __float2half_rn(w1[(k0+1)*64 + ht*16 + m]);
            w1frag[f] = (unsigned)__half_as_ushort(lo)
                      | ((unsigned)__half_as_ushort(hi) << 16);
        }
        return;
    }
    __shared__ unsigned short tile[256*33];
    int bp = blockIdx.x >> 8;
    int y  = blockIdx.x & 255;
    int t  = threadIdx.x;
    const float* s = src + (size_t)bp*PLANE_ELEMS + (size_t)y*256;
    #pragma unroll
    for (int c = 0; c < 32; ++c)
        tile[t*33 + c] = __half_as_ushort(__float2half_rn(s[(size_t)c*65536 + t]));
    __syncthreads();
    unsigned* d = reinterpret_cast<unsigned*>(dst + ((size_t)bp*65536 + (size_t)y*256)*32);
    #pragma unroll
    for (int it = 0; it < 16; ++it) {
        int q = it*256 + t;
        int x = q >> 4, c2 = q & 15;
        unsigned lo = tile[x*33 + 2*c2];
        unsigned hi = tile[x*33 + 2*c2 + 1];
        d[q] = lo | (hi << 16);
    }
}

// K1/K3: plane sampling + decoder MLP (MFMA). One block = 256 points.
// featT point-major [pt][16 u32], XOR-swizzled quad-groups; w1 GEMV on the
// matrix pipe (16 MFMA/wave); desc/featT are wave-local -> no block barrier
// between gather and MLP (s_waitcnt lgkmcnt(0), DS in-order per wave).
__global__ __launch_bounds__(256, 5) void k_sample_mlp(
    const __half* __restrict__ planesT,
    const float* __restrict__ orig, const float* __restrict__ dirs,
    const unsigned* __restrict__ w1frag, const float* __restrict__ b1,
    const float* __restrict__ w2, const float* __restrict__ b2,
    const float* __restrict__ dfine,
    float* __restrict__ colors, float* __restrict__ sigmas,
    int mode)
{
    __shared__ unsigned desc[256*12];   // [pt][12]: f16 weight<<16 | u16 texel
    __shared__ unsigned featT[256*16];  // [pt][16 c-pairs], swizzled
    __shared__ float b1s[64];
    __shared__ float w2s[256];          // row j = w2[j][0..3]

    int tid = threadIdx.x;
    int pid = blockIdx.x * 256 + tid;
    int rid = pid / 48;
    int s   = pid - rid*48;
    int b   = rid >> 12;

    // ---- phase 0: 12 packed tap descriptors for this thread's point ----
    float ox = orig[rid*3+0], oy = orig[rid*3+1], oz = orig[rid*3+2];
    float dxv = dirs[rid*3+0], dyv = dirs[rid*3+1], dzv = dirs[rid*3+2];
    float depth;
    if (mode == 0) {
        float cam = sqrtf(ox*ox + oy*oy + oz*oz);
        depth = coarse_depth(cam, s);
    } else {
        depth = dfine[(size_t)rid*48 + s];
    }
    float cx = ox + depth*dxv;
    float cy = oy + depth*dyv;
    float cz = oz + depth*dzv;
    float us[3] = {cx, cz, cy};   // p0 (x,y), p1 (z,x), p2 (y,z)
    float vs[3] = {cy, cx, cz};
    unsigned dpk[12];
    #pragma unroll
    for (int pl = 0; pl < 3; ++pl) {
        float xg = (us[pl] + 1.0f) * 0.5f * 256.0f - 0.5f;
        float yg = (vs[pl] + 1.0f) * 0.5f * 256.0f - 0.5f;
        float x0f = floorf(xg), y0f = floorf(yg);
        float wx = xg - x0f, wy = yg - y0f;
        int x0 = (int)x0f, y0 = (int)y0f;
        float tw[4] = {(1.0f-wx)*(1.0f-wy), wx*(1.0f-wy), (1.0f-wx)*wy, wx*wy};
        #pragma unroll
        for (int t4 = 0; t4 < 4; ++t4) {
            int xi = x0 + (t4 & 1);
            int yi = y0 + (t4 >> 1);
            bool valid = (xi >= 0) && (xi < 256) && (yi >= 0) && (yi < 256);
            int xc = min(max(xi, 0), 255);
            int yc = min(max(yi, 0), 255);
            float wv = valid ? tw[t4] : 0.0f;
            dpk[pl*4+t4] = ((unsigned)__half_as_ushort(__float2half_rn(wv)) << 16)
                         | (unsigned)(yc*256 + xc);
        }
    }
    #pragma unroll
    for (int q = 0; q < 6; ++q)
        *reinterpret_cast<uint2*>(&desc[tid*12 + 2*q]) = make_uint2(dpk[2*q], dpk[2*q+1]);
    if (tid < 64) {
        b1s[tid] = b1[tid];
        *reinterpret_cast<float4*>(&w2s[tid*4]) =
            *reinterpret_cast<const float4*>(&w2[tid*4]);
    }
    __syncthreads();   // covers desc (wave-local anyway) + b1s/w2s (cross-wave)

    // ---- phase 1: per-wave gather, 8 lanes/point, 8B taps, hfma2 ----
    int lane = tid & 63, wbase = tid & 192;
    int g8 = lane >> 3, sub = lane & 7, c0 = sub*4;
    const __half* pbase = planesT + (size_t)(b*3)*PLANE_ELEMS + c0;
    const __half2 inv3h = __float2half2_rn(1.0f/3.0f);
    #pragma unroll 2
    for (int it = 0; it < 8; ++it) {
        int pp = wbase + it*8 + g8;
        __half2 a01 = __float2half2_rn(0.0f);
        __half2 a23 = __float2half2_rn(0.0f);
        #pragma unroll
        for (int h6 = 0; h6 < 2; ++h6) {
            unsigned dd[6];
            #pragma unroll
            for (int q = 0; q < 3; ++q) {
                uint2 pr = *reinterpret_cast<const uint2*>(&desc[pp*12 + h6*6 + 2*q]);
                dd[2*q] = pr.x; dd[2*q+1] = pr.y;
            }
            uint2 v[6]; __half2 wv[6];
            #pragma unroll
            for (int q = 0; q < 6; ++q) {
                int tp = h6*6 + q;
                int tix = dd[q] & 0xFFFF;
                wv[q] = __half2half2(__ushort_as_half((unsigned short)(dd[q] >> 16)));
                v[q] = *reinterpret_cast<const uint2*>(
                    pbase + (size_t)(tp>>2)*PLANE_ELEMS + ((size_t)tix << 5));
            }
            #pragma unroll
            for (int q = 0; q < 6; ++q) {
                __half2 v01, v23;
                __builtin_memcpy(&v01, &v[q].x, 4);
                __builtin_memcpy(&v23, &v[q].y, 4);
                a01 = __hfma2(wv[q], v01, a01);
                a23 = __hfma2(wv[q], v23, a23);
            }
        }
        a01 = __hmul2(a01, inv3h);
        a23 = __hmul2(a23, inv3h);
        unsigned u01, u23;
        __builtin_memcpy(&u01, &a01, 4);
        __builtin_memcpy(&u23, &a23, 4);
        // swizzled write: c-pairs 2sub, 2sub+1 of point pp
        int base = pp*16 + (((sub>>1) ^ (pp&3)) << 2) + ((sub&1) << 1);
        *reinterpret_cast<uint2*>(&featT[base]) = make_uint2(u01, u23);
    }
    // wave-local LDS handoff: drain own DS writes; DS is in-order per wave
    asm volatile("s_waitcnt lgkmcnt(0)" ::: "memory");

    // ---- phase 2: MLP via MFMA f32_16x16x32_f16 ----
    int w    = tid >> 6;
    int quad = lane >> 4;
    int n    = lane & 15;
    f16x8 af[4];
    {
        const uint4* wf = reinterpret_cast<const uint4*>(w1frag);
        #pragma unroll
        for (int ht = 0; ht < 4; ++ht) {
            uint4 u = wf[ht*64 + lane];
            __builtin_memcpy(&af[ht], &u, 16);
        }
    }
    #pragma unroll
    for (int p = 0; p < 4; ++p) {
        int ptile = w*4 + p;
        int pt    = ptile*16 + n;
        uint4 bu = *reinterpret_cast<const uint4*>(
            &featT[pt*16 + ((quad ^ (pt&3)) << 2)]);
        f16x8 bf;
        __builtin_memcpy(&bf, &bu, 16);
        float o0=0.f, o1=0.f, o2=0.f, o3=0.f;
        #pragma unroll
        for (int ht = 0; ht < 4; ++ht) {
            f32x4 acc = {0.f, 0.f, 0.f, 0.f};
            acc = __builtin_amdgcn_mfma_f32_16x16x32_f16(af[ht], bf, acc, 0, 0, 0);
            float4 bb = *reinterpret_cast<const float4*>(&b1s[ht*16 + quad*4]);
            float bbv[4] = {bb.x, bb.y, bb.z, bb.w};
            #pragma unroll
            for (int r = 0; r < 4; ++r) {
                float hv = softplusf(acc[r] + bbv[r]);
                float4 wr = *reinterpret_cast<const float4*>(
                    &w2s[(ht*16 + quad*4 + r)*4]);
                o0 = fmaf(hv, wr.x, o0);
                o1 = fmaf(hv, wr.y, o1);
                o2 = fmaf(hv, wr.z, o2);
                o3 = fmaf(hv, wr.w, o3);
            }
        }
        o0 += __shfl_xor(o0, 16); o0 += __shfl_xor(o0, 32);
        o1 += __shfl_xor(o1, 16); o1 += __shfl_xor(o1, 32);
        o2 += __shfl_xor(o2, 16); o2 += __shfl_xor(o2, 32);
        o3 += __shfl_xor(o3, 16); o3 += __shfl_xor(o3, 32);
        int pid2 = blockIdx.x*256 + ptile*16 + n;
        int rid2 = pid2 / 48;
        int s2   = pid2 - rid2*48;
        int slot = rid2*96 + (mode ? 48 + s2 : s2);
        if (quad == 0) {
            sigmas[slot] = 10.0f * softplusf(-10.0f * (o0 + b2[0]));
        } else {
            float oc = (quad == 1) ? o1 : (quad == 2 ? o2 : o3);
            colors[(size_t)slot*3 + (quad-1)] =
                sigmoidf(oc + b2[quad]) * 1.002f - 0.001f;
        }
    }
}

// K2: per-ray coarse weights -> blurred pdf -> inverse-CDF fine depths.
__global__ __launch_bounds__(64) void k_importance(
    const float* __restrict__ orig, const float* __restrict__ sigmas,
    float* __restrict__ dfine)
{
    __shared__ float tile[64*49];
    int t  = threadIdx.x;
    int r0 = blockIdx.x * 64;
    for (int it = 0; it < 48; ++it) {
        int l  = it*64 + t;
        int ri = l / 48;
        int i  = l - ri*48;
        tile[ri*49 + i] = sigmas[(size_t)(r0+ri)*96 + i];
    }
    __syncthreads();
    int rid = r0 + t;
    float ox = orig[rid*3+0], oy = orig[rid*3+1], oz = orig[rid*3+2];
    float cam = sqrtf(ox*ox + oy*oy + oz*oz);

    float w[47];
    float T = 1.0f;
    float sp_ = tile[t*49 + 0];
    float dprev = coarse_depth(cam, 0);
    #pragma unroll
    for (int i = 0; i < 47; ++i) {
        float sc = tile[t*49 + i + 1];
        float dnext = coarse_depth(cam, i+1);
        float delta = dnext - dprev;
        float dm = 0.5f*(sp_ + sc);
        float a = 1.0f - __expf(-delta*dm);
        w[i] = a * T;
        T *= (1.0f - a + 1e-10f);
        sp_ = sc; dprev = dnext;
    }
    float Ssum = 0.0f;
    #pragma unroll
    for (int m = 0; m < 45; ++m) {
        float wm1 = fmaxf(w[m],   w[m+1]);
        float wm2 = fmaxf(w[m+1], w[m+2]);
        float wq = (0.5f*(wm1 + wm2) + 0.01f) + 1e-5f;
        tile[t*49 + m] = wq;
        Ssum += wq;
    }
    int idx = 1;
    float cprev = 0.0f;
    float ccur  = tile[t*49 + 0] / Ssum;
    for (int k = 0; k < 48; ++k) {
        float u = (float)k * (1.0f/47.0f);
        while (idx < 46 && ccur <= u) {
            cprev = ccur;
            idx++;
            if (idx < 46) ccur += tile[t*49 + (idx-1)] / Ssum;
        }
        int below = idx - 1;
        int above = min(idx, 45);
        float cb = cprev;
        float ca = (idx < 46) ? ccur : cprev;
        float bb = 0.5f*(coarse_depth(cam, below) + coarse_depth(cam, below+1));
        float ba = 0.5f*(coarse_depth(cam, above) + coarse_depth(cam, above+1));
        float d_ = ca - cb;
        float den = (d_ < 1e-5f) ? 1.0f : d_;
        dfine[(size_t)rid*48 + k] = bb + (u - cb)/den * (ba - bb);
    }
}

// K4: stable merge + final ray march; sample data staged coalesced into LDS.
__global__ __launch_bounds__(64) void k_final(
    const float* __restrict__ orig,
    const float* __restrict__ colors, const float* __restrict__ sigmas,
    const float* __restrict__ dfine, float* __restrict__ out)
{
    __shared__ float scol[32*289];
    __shared__ float ssig[32*97];
    __shared__ float sdf [32*49];
    int t  = threadIdx.x;
    int r0 = blockIdx.x * 32;

    {
        const float4* src = reinterpret_cast<const float4*>(colors + (size_t)r0*288);
        for (int q = t; q < 2304; q += 64) {
            float4 v = src[q];
            int e = q*4, row = e/288, col = e - row*288;
            scol[row*289+col+0] = v.x; scol[row*289+col+1] = v.y;
            scol[row*289+col+2] = v.z; scol[row*289+col+3] = v.w;
        }
    }
    {
        const float4* src = reinterpret_cast<const float4*>(sigmas + (size_t)r0*96);
        for (int q = t; q < 768; q += 64) {
            float4 v = src[q];
            int e = q*4, row = e/96, col = e - row*96;
            ssig[row*97+col+0] = v.x; ssig[row*97+col+1] = v.y;
            ssig[row*97+col+2] = v.z; ssig[row*97+col+3] = v.w;
        }
    }
    {
        const float4* src = reinterpret_cast<const float4*>(dfine + (size_t)r0*48);
        for (int q = t; q < 384; q += 64) {
            float4 v = src[q];
            int e = q*4, row = e/48, col = e - row*48;
            sdf[row*49+col+0] = v.x; sdf[row*49+col+1] = v.y;
            sdf[row*49+col+2] = v.z; sdf[row*49+col+3] = v.w;
        }
    }
    __syncthreads();
    if (t >= 32) return;

    int rid = r0 + t;
    float ox = orig[rid*3+0], oy = orig[rid*3+1], oz = orig[rid*3+2];
    float cam = sqrtf(ox*ox + oy*oy + oz*oz);
    int i = 0, j = 0;
    float T = 1.0f, rgb0=0.f, rgb1=0.f, rgb2=0.f, dep=0.f, wsum=0.f;
    float dprev=0.f, sprev=0.f, cp0=0.f, cp1=0.f, cp2=0.f;
    for (int m = 0; m < 96; ++m) {
        float dc = (i < 48) ? coarse_depth(cam, i) : 3.4e38f;
        float df = (j < 48) ? sdf[t*49 + j] : 3.4e38f;
        bool takec = dc <= df;                  // stable: coarse wins ties
        int slot = takec ? i : 48 + j;
        float dcur = takec ? dc : df;
        if (takec) ++i; else ++j;
        float sc = ssig[t*97 + slot];
        float c0 = scol[t*289 + slot*3+0];
        float c1 = scol[t*289 + slot*3+1];
        float c2 = scol[t*289 + slot*3+2];
        if (m > 0) {
            float delta = dcur - dprev;
            float dm = 0.5f*(sprev + sc);
            float zm = 0.5f*(dprev + dcur);
            float a = 1.0f - __expf(-delta*dm);
            float wgt = a * T;
            T *= (1.0f - a + 1e-10f);
            rgb0 += wgt*0.5f*(cp0 + c0);
            rgb1 += wgt*0.5f*(cp1 + c1);
            rgb2 += wgt*0.5f*(cp2 + c2);
            dep  += wgt*zm;
            wsum += wgt;
        }
        dprev = dcur; sprev = sc; cp0 = c0; cp1 = c1; cp2 = c2;
    }
    out[rid*3+0] = rgb0;
    out[rid*3+1] = rgb1;
    out[rid*3+2] = rgb2;
    out[16384*3 + rid] = dep;
    out[16384*4 + rid] = wsum;
}

extern "C" void kernel_launch(void* const* d_in, const int* in_sizes, int n_in,
                              void* d_out, int out_size, void* d_ws, size_t ws_size,
                              hipStream_t stream)
{
    const float* planes = (const float*)d_in[0];
    const float* orig   = (const float*)d_in[1];
    const float* dirs   = (const float*)d_in[2];
    const float* w1     = (const float*)d_in[3];
    const float* b1     = (const float*)d_in[4];
    const float* w2     = (const float*)d_in[5];
    const float* b2     = (const float*)d_in[6];
    float* out = (float*)d_out;

    float* ws = (float*)d_ws;
    size_t n_sig = (size_t)NB*NR*96;
    size_t n_col = n_sig*3;
    size_t n_df  = (size_t)NB*NR*48;
    float*  sig     = ws;
    float*  col     = sig + n_sig;
    float*  dfin    = col + n_col;
    __half* planesT = (__half*)(dfin + n_df);              // 8B-aligned
    unsigned* w1frag = (unsigned*)(planesT + (size_t)12*PLANE_ELEMS);

    k_transpose<<<3073, 256, 0, stream>>>(planes, planesT, w1, w1frag);
    k_sample_mlp<<<3072, 256, 0, stream>>>(planesT, orig, dirs,
                                           w1frag, b1, w2, b2, dfin, col, sig, 0);
    k_importance<<<256, 64, 0, stream>>>(orig, sig, dfin);
    k_sample_mlp<<<3072, 256, 0, stream>>>(planesT, orig, dirs,
                                           w1frag, b1, w2, b2, dfin, col, sig, 1);
    k_final<<<512, 64, 0, stream>>>(orig, col, sig, dfin, out);
}